// Round 7
// baseline (1247.795 us; speedup 1.0000x reference)
//
#include <hip/hip_runtime.h>
#include <cstdint>
#include <cstddef>

#define HW 16384  // 128*128
typedef float v2f __attribute__((ext_vector_type(2)));

// ---------------- weight pack: pairs of adjacent output channels ----------------
__global__ __launch_bounds__(256) void k_packw(const float* __restrict__ w1,
                                               const float* __restrict__ w2,
                                               v2f* __restrict__ w1p,
                                               v2f* __restrict__ w2p) {
  int i = blockIdx.x * 256 + threadIdx.x;
  if (i < 2250) {
    int m = i % 3, k = (i / 3) % 25, ic = (i / 75) % 6, ocg = i / 450;
    int g0 = ocg * 6 + 2 * m;
    w1p[i] = (v2f){w1[(g0 * 6 + ic) * 25 + k], w1[((g0 + 1) * 6 + ic) * 25 + k]};
  }
  i -= 2250;
  if (i >= 0 && i < 33750) {
    int m = i % 5, k = (i / 5) % 9, ic = (i / 45) % 30, ocg = i / 1350;
    int g0 = ocg * 10 + 2 * m;
    w2p[i] = (v2f){w2[(g0 * 30 + ic) * 9 + k], w2[((g0 + 1) * 30 + ic) * 9 + k]};
  }
}

// ---------------- conv1 + fire(15) + maxpool 2x2 ----------------
__global__ __launch_bounds__(256, 4) void k_conv1(const float* __restrict__ x,
                                                  const v2f* __restrict__ w1p,
                                                  uint8_t* __restrict__ spk_pool) {
  const int tile = blockIdx.x, ocg = blockIdx.y, t = blockIdx.z;
  const int oc0 = ocg * 6;
  const int tid = threadIdx.x;
  const int tx = tid & 15, ty = tid >> 4;
  const int px0 = (tile & 7) << 4, py0 = (tile >> 3) << 4;
  __shared__ float sx[2][36 * 38];
  const int iy0 = (py0 << 1) - 2, ix0 = (px0 << 1) - 2;  // pad=2

  int goff[6], soff[6];
  bool act[6];
#pragma unroll
  for (int j = 0; j < 6; ++j) {
    int idx = tid + 256 * j;
    bool a = idx < 1296;
    int r = idx / 36, c = idx - r * 36;
    int gy = iy0 + r, gx = ix0 + c;
    bool inb = a && (unsigned)gy < 256u && (unsigned)gx < 256u;
    goff[j] = inb ? ((gy << 8) + gx) : -1;
    soff[j] = a ? (r * 38 + c) : 0;
    act[j] = a;
  }

  v2f acc2[3][4];
#pragma unroll
  for (int m = 0; m < 3; ++m)
#pragma unroll
    for (int j = 0; j < 4; ++j) acc2[m][j] = (v2f){0.f, 0.f};

  const float* xt = x + ((size_t)(t * 6) << 16);
  float v[6];
#pragma unroll
  for (int j = 0; j < 6; ++j) v[j] = (goff[j] >= 0) ? xt[goff[j]] : 0.f;
#pragma unroll
  for (int j = 0; j < 6; ++j)
    if (act[j]) sx[0][soff[j]] = v[j];
  __syncthreads();

#pragma unroll
  for (int ic = 0; ic < 6; ++ic) {
    const int cur = ic & 1, nxt = cur ^ 1;
    if (ic < 5) {
      const float* xp = xt + ((size_t)(ic + 1) << 16);
#pragma unroll
      for (int j = 0; j < 6; ++j) v[j] = (goff[j] >= 0) ? xp[goff[j]] : 0.f;
    }
    float win_[6][6];
#pragma unroll
    for (int r = 0; r < 6; ++r) {
      float2 a = *(const float2*)&sx[cur][(2 * ty + r) * 38 + 2 * tx];
      float2 b = *(const float2*)&sx[cur][(2 * ty + r) * 38 + 2 * tx + 2];
      float2 c = *(const float2*)&sx[cur][(2 * ty + r) * 38 + 2 * tx + 4];
      win_[r][0] = a.x; win_[r][1] = a.y; win_[r][2] = b.x;
      win_[r][3] = b.y; win_[r][4] = c.x; win_[r][5] = c.y;
    }
    const v2f* wp = w1p + ((size_t)(ocg * 6 + ic) * 25) * 3;
#pragma unroll
    for (int k = 0; k < 25; ++k) {
      const int ky = k / 5, kx = k % 5;
      v2f s0 = (v2f){win_[ky][kx], win_[ky][kx]};
      v2f s1 = (v2f){win_[ky][kx + 1], win_[ky][kx + 1]};
      v2f s2 = (v2f){win_[ky + 1][kx], win_[ky + 1][kx]};
      v2f s3 = (v2f){win_[ky + 1][kx + 1], win_[ky + 1][kx + 1]};
#pragma unroll
      for (int m = 0; m < 3; ++m) {
        v2f wv = wp[k * 3 + m];  // block-uniform -> SGPR pair
        acc2[m][0] += wv * s0;
        acc2[m][1] += wv * s1;
        acc2[m][2] += wv * s2;
        acc2[m][3] += wv * s3;
      }
    }
    if (ic < 5) {
#pragma unroll
      for (int j = 0; j < 6; ++j)
        if (act[j]) sx[nxt][soff[j]] = v[j];
    }
    __syncthreads();
  }
#pragma unroll
  for (int g = 0; g < 6; ++g) {
    const int m = g >> 1;
    float a0 = (g & 1) ? acc2[m][0].y : acc2[m][0].x;
    float a1 = (g & 1) ? acc2[m][1].y : acc2[m][1].x;
    float a2 = (g & 1) ? acc2[m][2].y : acc2[m][2].x;
    float a3 = (g & 1) ? acc2[m][3].y : acc2[m][3].x;
    int spike = (a0 > 15.f) || (a1 > 15.f) || (a2 > 15.f) || (a3 > 15.f);
    spk_pool[((size_t)(t * 30 + oc0 + g) << 14) + ((size_t)(py0 + ty) << 7) + (px0 + tx)] =
        (uint8_t)spike;
  }
}

// ---------------- conv2 (pad=1) + fire(10) -> pot2, fused channel-max atomics -----------
__global__ __launch_bounds__(256, 4) void k_conv2(const uint8_t* __restrict__ spk_pool,
                                                  const v2f* __restrict__ w2p,
                                                  float* __restrict__ pot2,
                                                  unsigned long long* __restrict__ mp) {
  const int tile = blockIdx.x, ocg = blockIdx.y, t = blockIdx.z;
  const int oc0 = ocg * 10;
  const int tid = threadIdx.x;
  const int bx = (tile & 3) << 5, by = (tile >> 2) << 5;
  const int tx = tid & 15, ty = tid >> 4;
  __shared__ float sS[2][34 * 40];
  __shared__ int sFlag[2][4];

  int goff[5], soff[5];
  bool act[5];
#pragma unroll
  for (int j = 0; j < 5; ++j) {
    int idx = tid + 256 * j;
    bool a = idx < 1156;
    int r = idx / 34, c = idx - r * 34;
    int gy = by - 1 + r, gx = bx - 1 + c;
    bool inb = a && (unsigned)gy < 128u && (unsigned)gx < 128u;
    goff[j] = inb ? ((gy << 7) + gx) : -1;
    soff[j] = a ? (r * 40 + c) : 0;
    act[j] = a;
  }

  v2f acc2[5][4];
#pragma unroll
  for (int m = 0; m < 5; ++m)
#pragma unroll
    for (int j = 0; j < 4; ++j) acc2[m][j] = (v2f){0.f, 0.f};

  const uint8_t* spk_t = spk_pool + ((size_t)(t * 30) << 14);
  float v[5];
#pragma unroll
  for (int j = 0; j < 5; ++j) v[j] = (goff[j] >= 0) ? (float)spk_t[goff[j]] : 0.f;
  {
    bool nz = (v[0] + v[1] + v[2] + v[3] + v[4]) != 0.f;
    bool wnz = __any(nz);
    if ((tid & 63) == 0) sFlag[0][tid >> 6] = wnz ? 1 : 0;
  }
#pragma unroll
  for (int j = 0; j < 5; ++j)
    if (act[j]) sS[0][soff[j]] = v[j];
  __syncthreads();

#pragma unroll 2
  for (int ic = 0; ic < 30; ++ic) {
    const int cur = ic & 1, nxt = cur ^ 1;
    if (ic < 29) {
      const uint8_t* spc = spk_t + ((size_t)(ic + 1) << 14);
#pragma unroll
      for (int j = 0; j < 5; ++j) v[j] = (goff[j] >= 0) ? (float)spc[goff[j]] : 0.f;
    }
    const int flag = sFlag[cur][0] | sFlag[cur][1] | sFlag[cur][2] | sFlag[cur][3];
    if (flag) {
      float win_[4][4];
#pragma unroll
      for (int r = 0; r < 4; ++r) {
        float2 a = *(const float2*)&sS[cur][(2 * ty + r) * 40 + 2 * tx];
        float2 b = *(const float2*)&sS[cur][(2 * ty + r) * 40 + 2 * tx + 2];
        win_[r][0] = a.x; win_[r][1] = a.y; win_[r][2] = b.x; win_[r][3] = b.y;
      }
      const v2f* wp = w2p + ((size_t)(ocg * 30 + ic) * 9) * 5;
#pragma unroll
      for (int k = 0; k < 9; ++k) {
        const int kr = k / 3, ks = k % 3;
        v2f s0 = (v2f){win_[kr][ks], win_[kr][ks]};
        v2f s1 = (v2f){win_[kr][ks + 1], win_[kr][ks + 1]};
        v2f s2 = (v2f){win_[kr + 1][ks], win_[kr + 1][ks]};
        v2f s3 = (v2f){win_[kr + 1][ks + 1], win_[kr + 1][ks + 1]};
#pragma unroll
        for (int m = 0; m < 5; ++m) {
          v2f wv = wp[k * 5 + m];  // block-uniform -> SGPR pair
          acc2[m][0] += wv * s0;
          acc2[m][1] += wv * s1;
          acc2[m][2] += wv * s2;
          acc2[m][3] += wv * s3;
        }
      }
    }
    if (ic < 29) {
      bool nz = (v[0] + v[1] + v[2] + v[3] + v[4]) != 0.f;
      bool wnz = __any(nz);
      if ((tid & 63) == 0) sFlag[nxt][tid >> 6] = wnz ? 1 : 0;
#pragma unroll
      for (int j = 0; j < 5; ++j)
        if (act[j]) sS[nxt][soff[j]] = v[j];
    }
    __syncthreads();
  }

  // fire + write pot2 + per-loc max/argmax over this block's 10 oc
  const int gy = by + 2 * ty, gx = bx + 2 * tx;
  float mxv[4] = {0.f, 0.f, 0.f, 0.f};
  int mxc[4] = {0, 0, 0, 0};
#pragma unroll
  for (int g = 0; g < 10; ++g) {
    const int m = g >> 1;
    float a0 = (g & 1) ? acc2[m][0].y : acc2[m][0].x;
    float a1 = (g & 1) ? acc2[m][1].y : acc2[m][1].x;
    float a2 = (g & 1) ? acc2[m][2].y : acc2[m][2].x;
    float a3 = (g & 1) ? acc2[m][3].y : acc2[m][3].x;
    float* outp = pot2 + ((size_t)(t * 250 + oc0 + g) << 14);
    float2 v0, v1;
    v0.x = a0 > 10.f ? a0 : 0.f;
    v0.y = a1 > 10.f ? a1 : 0.f;
    v1.x = a2 > 10.f ? a2 : 0.f;
    v1.y = a3 > 10.f ? a3 : 0.f;
    *(float2*)&outp[((size_t)gy << 7) + gx] = v0;
    *(float2*)&outp[((size_t)(gy + 1) << 7) + gx] = v1;
    if (v0.x > mxv[0]) { mxv[0] = v0.x; mxc[0] = g; }
    if (v0.y > mxv[1]) { mxv[1] = v0.y; mxc[1] = g; }
    if (v1.x > mxv[2]) { mxv[2] = v1.x; mxc[2] = g; }
    if (v1.y > mxv[3]) { mxv[3] = v1.y; mxc[3] = g; }
  }
  unsigned long long* mpt = mp + (size_t)t * HW;
  const int locs[4] = {(gy << 7) + gx, (gy << 7) + gx + 1,
                       ((gy + 1) << 7) + gx, ((gy + 1) << 7) + gx + 1};
#pragma unroll
  for (int j = 0; j < 4; ++j) {
    unsigned long long pk =
        ((unsigned long long)__float_as_uint(mxv[j]) << 32) |
        (unsigned long long)(1023 - (oc0 + mxc[j]));
    atomicMax(&mpt[locs[j]], pk);
  }
}

// ---------------- inhibition combine per location ----------------
__global__ __launch_bounds__(64) void k_inhib(const float* __restrict__ pot2,
                                              const unsigned long long* __restrict__ mp,
                                              int* __restrict__ win,
                                              float* __restrict__ nspv,
                                              float* __restrict__ valv,
                                              float* __restrict__ sv) {
  const int loc = (blockIdx.x << 6) + threadIdx.x;
  int cnt = 0;
  float last = 0.f;
  unsigned long long pks[15];
#pragma unroll
  for (int t = 0; t < 15; ++t) {
    pks[t] = mp[t * HW + loc];
    float v = __uint_as_float((unsigned)(pks[t] >> 32));
    cnt += (v > 0.f) ? 1 : 0;
    if (t == 14) last = v;
  }
  const int spiked = (last > 0.f) ? 1 : 0;
  int ft = 15 - cnt;
  if (ft > 14) ft = 14;
  if (ft < 0) ft = 0;
  int wc = 1023 - (int)(pks[ft] & 1023ULL);
  if ((unsigned)wc > 249u) wc = 0;
  int nsp = 0;
#pragma unroll
  for (int t = 0; t < 15; ++t) {
    float v = pot2[((size_t)(t * 250 + wc) << 14) + loc];
    v = spiked ? v : 0.f;
    sv[t * HW + loc] = v;
    nsp += (v > 0.f) ? 1 : 0;
  }
  int ft2 = 15 - nsp;
  if (ft2 > 14) ft2 = 14;
  float value = spiked ? pot2[((size_t)(ft2 * 250 + wc) << 14) + loc] : 0.f;
  win[loc] = spiked ? wc : -1;
  nspv[loc] = (float)nsp;
  valv[loc] = value;
}

// ---------------- finalize: plane-major, sequential 64KB writes per block ----------------
// grid (250 c, 15 t), block 256. Thread: 16 float4 chunks of one plane.
__global__ __launch_bounds__(256) void k_final(const int* __restrict__ win,
                                               const float* __restrict__ sv,
                                               float* __restrict__ spk_out,
                                               float* __restrict__ pot_out) {
  const int c = blockIdx.x, t = blockIdx.y;
  const int tid = threadIdx.x;
  const float* svt = sv + t * HW;
  float* pp = pot_out + ((size_t)(t * 250 + c) << 14);
  float* sp = spk_out + ((size_t)(t * 250 + c) << 14);
  for (int i = tid * 4; i < HW; i += 1024) {
    int4 w4 = *(const int4*)&win[i];
    float4 v4 = *(const float4*)&svt[i];
    float4 pv, sw;
    pv.x = (w4.x == c) ? v4.x : 0.f; sw.x = (w4.x == c && v4.x > 0.f) ? 1.f : 0.f;
    pv.y = (w4.y == c) ? v4.y : 0.f; sw.y = (w4.y == c && v4.y > 0.f) ? 1.f : 0.f;
    pv.z = (w4.z == c) ? v4.z : 0.f; sw.z = (w4.z == c && v4.z > 0.f) ? 1.f : 0.f;
    pv.w = (w4.w == c) ? v4.w : 0.f; sw.w = (w4.w == c && v4.w > 0.f) ? 1.f : 0.f;
    *(float4*)&pp[i] = pv;
    *(float4*)&sp[i] = sw;
  }
}

// ---------------- k-winner selection (single block) ----------------
__global__ __launch_bounds__(256) void k_select(const int* __restrict__ win,
                                                const float* __restrict__ nspv,
                                                const float* __restrict__ valv,
                                                float* __restrict__ winners) {
  __shared__ float tot[HW];
  __shared__ int wchan[HW];
  __shared__ float redV[256];
  __shared__ int redK[256];
  __shared__ float bcValid[1];
  __shared__ int bcKey[1];
  const int tid = threadIdx.x;

  float lmax = 0.f;
  for (int i = tid; i < HW; i += 256) {
    wchan[i] = win[i];
    lmax = fmaxf(lmax, valv[i]);
  }
  redV[tid] = lmax;
  __syncthreads();
  for (int s = 128; s > 0; s >>= 1) {
    if (tid < s) redV[tid] = fmaxf(redV[tid], redV[tid + s]);
    __syncthreads();
  }
  const float v15 = redV[0] * 15.f;
  __syncthreads();
  for (int i = tid; i < HW; i += 256) tot[i] = nspv[i] * (valv[i] + v15);
  __syncthreads();

  for (int k = 0; k < 8; ++k) {
    float bv = -1.f;
    int bkey = 0x7fffffff;
    for (int i = tid; i < HW; i += 256) {
      float v = tot[i];
      int key = (wchan[i] << 14) + i;
      if (v > bv || (v == bv && key < bkey)) { bv = v; bkey = key; }
    }
    redV[tid] = bv;
    redK[tid] = bkey;
    __syncthreads();
    for (int s = 128; s > 0; s >>= 1) {
      if (tid < s) {
        float ov = redV[tid + s];
        int ok = redK[tid + s];
        if (ov > redV[tid] || (ov == redV[tid] && ok < redK[tid])) {
          redV[tid] = ov;
          redK[tid] = ok;
        }
      }
      __syncthreads();
    }
    if (tid == 0) {
      float mv = redV[0];
      int mk = redK[0];
      int valid = (mv != 0.f) ? 1 : 0;
      int c = mk >> 14, l = mk & (HW - 1);
      winners[k * 3 + 0] = valid ? (float)c : -1.f;
      winners[k * 3 + 1] = valid ? (float)(l >> 7) : -1.f;
      winners[k * 3 + 2] = valid ? (float)(l & 127) : -1.f;
      bcValid[0] = valid ? 1.f : 0.f;
      bcKey[0] = mk;
    }
    __syncthreads();
    if (bcValid[0] > 0.f) {
      int mk = bcKey[0];
      int c = mk >> 14, h = (mk & (HW - 1)) >> 7, w = mk & 127;
      for (int i = tid; i < HW; i += 256) {
        int hh = i >> 7, ww = i & 127;
        int dh = hh - h; if (dh < 0) dh = -dh;
        int dw = ww - w; if (dw < 0) dw = -dw;
        bool m = (wchan[i] == c) || (dh <= 1 && dw <= 1);
        if (m) tot[i] = 0.f;
      }
    }
    __syncthreads();
  }
}

extern "C" void kernel_launch(void* const* d_in, const int* in_sizes, int n_in,
                              void* d_out, int out_size, void* d_ws, size_t ws_size,
                              hipStream_t stream) {
  const float* x = (const float*)d_in[0];
  const float* w1 = (const float*)d_in[1];
  const float* w2 = (const float*)d_in[2];
  (void)in_sizes; (void)n_in; (void)out_size; (void)ws_size;

  float* spk_out = (float*)d_out;
  float* pot_out = spk_out + 61440000;  // pot2 scratch == final pot at winner ch
  float* winners = spk_out + 122880000;

  uint8_t* ws = (uint8_t*)d_ws;
  unsigned long long* mp = (unsigned long long*)ws;  // 1,966,080 B u64 [15][HW]
  uint8_t* spk_pool = ws + 1966080;                  // 7,372,800 B u8
  int* win = (int*)(ws + 9338880);        //  65,536 B
  float* nspv = (float*)(ws + 9404416);   //  65,536 B
  float* valv = (float*)(ws + 9469952);   //  65,536 B
  float* sv = (float*)(ws + 9535488);     // 983,040 B  [15][16384]
  v2f* w1p = (v2f*)(ws + 10518528);       //  18,000 B
  v2f* w2p = (v2f*)(ws + 10536528);       // 270,000 B

  hipMemsetAsync(mp, 0, (size_t)15 * HW * 8, stream);
  hipLaunchKernelGGL(k_packw, dim3(141), dim3(256), 0, stream, w1, w2, w1p, w2p);
  hipLaunchKernelGGL(k_conv1, dim3(64, 5, 15), dim3(256), 0, stream, x, w1p, spk_pool);
  hipLaunchKernelGGL(k_conv2, dim3(16, 25, 15), dim3(256), 0, stream, spk_pool, w2p, pot_out, mp);
  hipLaunchKernelGGL(k_inhib, dim3(256), dim3(64), 0, stream, pot_out, mp, win, nspv, valv, sv);
  hipLaunchKernelGGL(k_final, dim3(250, 15), dim3(256), 0, stream, win, sv, spk_out, pot_out);
  hipLaunchKernelGGL(k_select, dim3(1), dim3(256), 0, stream, win, nspv, valv, winners);
}

// Round 8
// 1163.418 us; speedup vs baseline: 1.0725x; 1.0725x over previous
//
#include <hip/hip_runtime.h>
#include <cstdint>
#include <cstddef>

#define HW 16384  // 128*128
typedef float v2f __attribute__((ext_vector_type(2)));

// ---------------- weight pack: pairs of adjacent output channels ----------------
__global__ __launch_bounds__(256) void k_packw(const float* __restrict__ w1,
                                               const float* __restrict__ w2,
                                               v2f* __restrict__ w1p,
                                               v2f* __restrict__ w2p) {
  int i = blockIdx.x * 256 + threadIdx.x;
  if (i < 2250) {
    int m = i % 3, k = (i / 3) % 25, ic = (i / 75) % 6, ocg = i / 450;
    int g0 = ocg * 6 + 2 * m;
    w1p[i] = (v2f){w1[(g0 * 6 + ic) * 25 + k], w1[((g0 + 1) * 6 + ic) * 25 + k]};
  }
  i -= 2250;
  if (i >= 0 && i < 33750) {
    int m = i % 5, k = (i / 5) % 9, ic = (i / 45) % 30, ocg = i / 1350;
    int g0 = ocg * 10 + 2 * m;
    w2p[i] = (v2f){w2[(g0 * 30 + ic) * 9 + k], w2[((g0 + 1) * 30 + ic) * 9 + k]};
  }
}

// ---------------- conv1 + fire(15) + maxpool 2x2 (round-6 exact) ----------------
__global__ __launch_bounds__(256, 4) void k_conv1(const float* __restrict__ x,
                                                  const v2f* __restrict__ w1p,
                                                  uint8_t* __restrict__ spk_pool) {
  const int tile = blockIdx.x, ocg = blockIdx.y, t = blockIdx.z;
  const int oc0 = ocg * 6;
  const int tid = threadIdx.x;
  const int tx = tid & 15, ty = tid >> 4;
  const int px0 = (tile & 7) << 4, py0 = (tile >> 3) << 4;
  __shared__ float sx[2][36 * 38];
  const int iy0 = (py0 << 1) - 2, ix0 = (px0 << 1) - 2;  // pad=2

  int goff[6], soff[6];
  bool act[6];
#pragma unroll
  for (int j = 0; j < 6; ++j) {
    int idx = tid + 256 * j;
    bool a = idx < 1296;
    int r = idx / 36, c = idx - r * 36;
    int gy = iy0 + r, gx = ix0 + c;
    bool inb = a && (unsigned)gy < 256u && (unsigned)gx < 256u;
    goff[j] = inb ? ((gy << 8) + gx) : -1;
    soff[j] = a ? (r * 38 + c) : 0;
    act[j] = a;
  }

  v2f acc2[3][4];
#pragma unroll
  for (int m = 0; m < 3; ++m)
#pragma unroll
    for (int j = 0; j < 4; ++j) acc2[m][j] = (v2f){0.f, 0.f};

  const float* xt = x + ((size_t)(t * 6) << 16);
  float v[6];
#pragma unroll
  for (int j = 0; j < 6; ++j) v[j] = (goff[j] >= 0) ? xt[goff[j]] : 0.f;
#pragma unroll
  for (int j = 0; j < 6; ++j)
    if (act[j]) sx[0][soff[j]] = v[j];
  __syncthreads();

  for (int ic = 0; ic < 6; ++ic) {
    const int cur = ic & 1, nxt = cur ^ 1;
    if (ic < 5) {
      const float* xp = xt + ((size_t)(ic + 1) << 16);
#pragma unroll
      for (int j = 0; j < 6; ++j) v[j] = (goff[j] >= 0) ? xp[goff[j]] : 0.f;
    }
    float win_[6][6];
#pragma unroll
    for (int r = 0; r < 6; ++r) {
      float2 a = *(const float2*)&sx[cur][(2 * ty + r) * 38 + 2 * tx];
      float2 b = *(const float2*)&sx[cur][(2 * ty + r) * 38 + 2 * tx + 2];
      float2 c = *(const float2*)&sx[cur][(2 * ty + r) * 38 + 2 * tx + 4];
      win_[r][0] = a.x; win_[r][1] = a.y; win_[r][2] = b.x;
      win_[r][3] = b.y; win_[r][4] = c.x; win_[r][5] = c.y;
    }
    const v2f* wp = w1p + ((size_t)(ocg * 6 + ic) * 25) * 3;
#pragma unroll
    for (int k = 0; k < 25; ++k) {
      const int ky = k / 5, kx = k % 5;
      v2f s0 = (v2f){win_[ky][kx], win_[ky][kx]};
      v2f s1 = (v2f){win_[ky][kx + 1], win_[ky][kx + 1]};
      v2f s2 = (v2f){win_[ky + 1][kx], win_[ky + 1][kx]};
      v2f s3 = (v2f){win_[ky + 1][kx + 1], win_[ky + 1][kx + 1]};
#pragma unroll
      for (int m = 0; m < 3; ++m) {
        v2f wv = wp[k * 3 + m];  // block-uniform -> SGPR pair
        acc2[m][0] += wv * s0;
        acc2[m][1] += wv * s1;
        acc2[m][2] += wv * s2;
        acc2[m][3] += wv * s3;
      }
    }
    if (ic < 5) {
#pragma unroll
      for (int j = 0; j < 6; ++j)
        if (act[j]) sx[nxt][soff[j]] = v[j];
    }
    __syncthreads();
  }
#pragma unroll
  for (int g = 0; g < 6; ++g) {
    const int m = g >> 1;
    float a0 = (g & 1) ? acc2[m][0].y : acc2[m][0].x;
    float a1 = (g & 1) ? acc2[m][1].y : acc2[m][1].x;
    float a2 = (g & 1) ? acc2[m][2].y : acc2[m][2].x;
    float a3 = (g & 1) ? acc2[m][3].y : acc2[m][3].x;
    int spike = (a0 > 15.f) || (a1 > 15.f) || (a2 > 15.f) || (a3 > 15.f);
    spk_pool[((size_t)(t * 30 + oc0 + g) << 14) + ((size_t)(py0 + ty) << 7) + (px0 + tx)] =
        (uint8_t)spike;
  }
}

// ---------------- conv2 (pad=1) + fire(10) -> pot2, fused channel-max (round-6 exact) ----
__global__ __launch_bounds__(256, 4) void k_conv2(const uint8_t* __restrict__ spk_pool,
                                                  const v2f* __restrict__ w2p,
                                                  float* __restrict__ pot2,
                                                  unsigned long long* __restrict__ mp) {
  const int tile = blockIdx.x, ocg = blockIdx.y, t = blockIdx.z;
  const int oc0 = ocg * 10;
  const int tid = threadIdx.x;
  const int bx = (tile & 3) << 5, by = (tile >> 2) << 5;
  const int tx = tid & 15, ty = tid >> 4;
  __shared__ float sS[2][34 * 40];
  __shared__ int sFlag[2][4];

  int goff[5], soff[5];
  bool act[5];
#pragma unroll
  for (int j = 0; j < 5; ++j) {
    int idx = tid + 256 * j;
    bool a = idx < 1156;
    int r = idx / 34, c = idx - r * 34;
    int gy = by - 1 + r, gx = bx - 1 + c;
    bool inb = a && (unsigned)gy < 128u && (unsigned)gx < 128u;
    goff[j] = inb ? ((gy << 7) + gx) : -1;
    soff[j] = a ? (r * 40 + c) : 0;
    act[j] = a;
  }

  v2f acc2[5][4];
#pragma unroll
  for (int m = 0; m < 5; ++m)
#pragma unroll
    for (int j = 0; j < 4; ++j) acc2[m][j] = (v2f){0.f, 0.f};

  const uint8_t* spk_t = spk_pool + ((size_t)(t * 30) << 14);
  float v[5];
#pragma unroll
  for (int j = 0; j < 5; ++j) v[j] = (goff[j] >= 0) ? (float)spk_t[goff[j]] : 0.f;
  {
    bool nz = (v[0] + v[1] + v[2] + v[3] + v[4]) != 0.f;
    bool wnz = __any(nz);
    if ((tid & 63) == 0) sFlag[0][tid >> 6] = wnz ? 1 : 0;
  }
#pragma unroll
  for (int j = 0; j < 5; ++j)
    if (act[j]) sS[0][soff[j]] = v[j];
  __syncthreads();

  for (int ic = 0; ic < 30; ++ic) {
    const int cur = ic & 1, nxt = cur ^ 1;
    if (ic < 29) {
      const uint8_t* spc = spk_t + ((size_t)(ic + 1) << 14);
#pragma unroll
      for (int j = 0; j < 5; ++j) v[j] = (goff[j] >= 0) ? (float)spc[goff[j]] : 0.f;
    }
    const int flag = sFlag[cur][0] | sFlag[cur][1] | sFlag[cur][2] | sFlag[cur][3];
    if (flag) {
      float win_[4][4];
#pragma unroll
      for (int r = 0; r < 4; ++r) {
        float2 a = *(const float2*)&sS[cur][(2 * ty + r) * 40 + 2 * tx];
        float2 b = *(const float2*)&sS[cur][(2 * ty + r) * 40 + 2 * tx + 2];
        win_[r][0] = a.x; win_[r][1] = a.y; win_[r][2] = b.x; win_[r][3] = b.y;
      }
      const v2f* wp = w2p + ((size_t)(ocg * 30 + ic) * 9) * 5;
#pragma unroll
      for (int k = 0; k < 9; ++k) {
        const int kr = k / 3, ks = k % 3;
        v2f s0 = (v2f){win_[kr][ks], win_[kr][ks]};
        v2f s1 = (v2f){win_[kr][ks + 1], win_[kr][ks + 1]};
        v2f s2 = (v2f){win_[kr + 1][ks], win_[kr + 1][ks]};
        v2f s3 = (v2f){win_[kr + 1][ks + 1], win_[kr + 1][ks + 1]};
#pragma unroll
        for (int m = 0; m < 5; ++m) {
          v2f wv = wp[k * 5 + m];  // block-uniform -> SGPR pair
          acc2[m][0] += wv * s0;
          acc2[m][1] += wv * s1;
          acc2[m][2] += wv * s2;
          acc2[m][3] += wv * s3;
        }
      }
    }
    if (ic < 29) {
      bool nz = (v[0] + v[1] + v[2] + v[3] + v[4]) != 0.f;
      bool wnz = __any(nz);
      if ((tid & 63) == 0) sFlag[nxt][tid >> 6] = wnz ? 1 : 0;
#pragma unroll
      for (int j = 0; j < 5; ++j)
        if (act[j]) sS[nxt][soff[j]] = v[j];
    }
    __syncthreads();
  }

  // fire + write pot2 + per-loc max/argmax over this block's 10 oc
  const int gy = by + 2 * ty, gx = bx + 2 * tx;
  float mxv[4] = {0.f, 0.f, 0.f, 0.f};
  int mxc[4] = {0, 0, 0, 0};
#pragma unroll
  for (int g = 0; g < 10; ++g) {
    const int m = g >> 1;
    float a0 = (g & 1) ? acc2[m][0].y : acc2[m][0].x;
    float a1 = (g & 1) ? acc2[m][1].y : acc2[m][1].x;
    float a2 = (g & 1) ? acc2[m][2].y : acc2[m][2].x;
    float a3 = (g & 1) ? acc2[m][3].y : acc2[m][3].x;
    float* outp = pot2 + ((size_t)(t * 250 + oc0 + g) << 14);
    float2 v0, v1;
    v0.x = a0 > 10.f ? a0 : 0.f;
    v0.y = a1 > 10.f ? a1 : 0.f;
    v1.x = a2 > 10.f ? a2 : 0.f;
    v1.y = a3 > 10.f ? a3 : 0.f;
    *(float2*)&outp[((size_t)gy << 7) + gx] = v0;
    *(float2*)&outp[((size_t)(gy + 1) << 7) + gx] = v1;
    if (v0.x > mxv[0]) { mxv[0] = v0.x; mxc[0] = g; }
    if (v0.y > mxv[1]) { mxv[1] = v0.y; mxc[1] = g; }
    if (v1.x > mxv[2]) { mxv[2] = v1.x; mxc[2] = g; }
    if (v1.y > mxv[3]) { mxv[3] = v1.y; mxc[3] = g; }
  }
  unsigned long long* mpt = mp + (size_t)t * HW;
  const int locs[4] = {(gy << 7) + gx, (gy << 7) + gx + 1,
                       ((gy + 1) << 7) + gx, ((gy + 1) << 7) + gx + 1};
#pragma unroll
  for (int j = 0; j < 4; ++j) {
    unsigned long long pk =
        ((unsigned long long)__float_as_uint(mxv[j]) << 32) |
        (unsigned long long)(1023 - (oc0 + mxc[j]));
    atomicMax(&mpt[locs[j]], pk);
  }
}

// ---------------- inhibition combine per location ----------------
__global__ __launch_bounds__(64) void k_inhib(const float* __restrict__ pot2,
                                              const unsigned long long* __restrict__ mp,
                                              int* __restrict__ win,
                                              float* __restrict__ nspv,
                                              float* __restrict__ valv,
                                              float* __restrict__ sv) {
  const int loc = (blockIdx.x << 6) + threadIdx.x;
  int cnt = 0;
  float last = 0.f;
  unsigned long long pks[15];
#pragma unroll
  for (int t = 0; t < 15; ++t) {
    pks[t] = mp[t * HW + loc];
    float v = __uint_as_float((unsigned)(pks[t] >> 32));
    cnt += (v > 0.f) ? 1 : 0;
    if (t == 14) last = v;
  }
  const int spiked = (last > 0.f) ? 1 : 0;
  int ft = 15 - cnt;
  if (ft > 14) ft = 14;
  if (ft < 0) ft = 0;
  int wc = 1023 - (int)(pks[ft] & 1023ULL);
  if ((unsigned)wc > 249u) wc = 0;
  int nsp = 0;
#pragma unroll
  for (int t = 0; t < 15; ++t) {
    float v = pot2[((size_t)(t * 250 + wc) << 14) + loc];
    v = spiked ? v : 0.f;
    sv[t * HW + loc] = v;
    nsp += (v > 0.f) ? 1 : 0;
  }
  int ft2 = 15 - nsp;
  if (ft2 > 14) ft2 = 14;
  float value = spiked ? pot2[((size_t)(ft2 * 250 + wc) << 14) + loc] : 0.f;
  win[loc] = spiked ? wc : -1;
  nspv[loc] = (float)nsp;
  valv[loc] = value;
}

// ---------------- finalize: plane-major, sequential 64KB writes per block ----------------
// grid (250 c, 15 t), block 256. Thread: 16 float4 chunks of one plane.
__global__ __launch_bounds__(256) void k_final(const int* __restrict__ win,
                                               const float* __restrict__ sv,
                                               float* __restrict__ spk_out,
                                               float* __restrict__ pot_out) {
  const int c = blockIdx.x, t = blockIdx.y;
  const int tid = threadIdx.x;
  const float* svt = sv + t * HW;
  float* pp = pot_out + ((size_t)(t * 250 + c) << 14);
  float* sp = spk_out + ((size_t)(t * 250 + c) << 14);
  for (int i = tid * 4; i < HW; i += 1024) {
    int4 w4 = *(const int4*)&win[i];
    float4 v4 = *(const float4*)&svt[i];
    float4 pv, sw;
    pv.x = (w4.x == c) ? v4.x : 0.f; sw.x = (w4.x == c && v4.x > 0.f) ? 1.f : 0.f;
    pv.y = (w4.y == c) ? v4.y : 0.f; sw.y = (w4.y == c && v4.y > 0.f) ? 1.f : 0.f;
    pv.z = (w4.z == c) ? v4.z : 0.f; sw.z = (w4.z == c && v4.z > 0.f) ? 1.f : 0.f;
    pv.w = (w4.w == c) ? v4.w : 0.f; sw.w = (w4.w == c && v4.w > 0.f) ? 1.f : 0.f;
    *(float4*)&pp[i] = pv;
    *(float4*)&sp[i] = sw;
  }
}

// ---------------- k-winner selection (single block) ----------------
__global__ __launch_bounds__(256) void k_select(const int* __restrict__ win,
                                                const float* __restrict__ nspv,
                                                const float* __restrict__ valv,
                                                float* __restrict__ winners) {
  __shared__ float tot[HW];
  __shared__ int wchan[HW];
  __shared__ float redV[256];
  __shared__ int redK[256];
  __shared__ float bcValid[1];
  __shared__ int bcKey[1];
  const int tid = threadIdx.x;

  float lmax = 0.f;
  for (int i = tid; i < HW; i += 256) {
    wchan[i] = win[i];
    lmax = fmaxf(lmax, valv[i]);
  }
  redV[tid] = lmax;
  __syncthreads();
  for (int s = 128; s > 0; s >>= 1) {
    if (tid < s) redV[tid] = fmaxf(redV[tid], redV[tid + s]);
    __syncthreads();
  }
  const float v15 = redV[0] * 15.f;
  __syncthreads();
  for (int i = tid; i < HW; i += 256) tot[i] = nspv[i] * (valv[i] + v15);
  __syncthreads();

  for (int k = 0; k < 8; ++k) {
    float bv = -1.f;
    int bkey = 0x7fffffff;
    for (int i = tid; i < HW; i += 256) {
      float v = tot[i];
      int key = (wchan[i] << 14) + i;
      if (v > bv || (v == bv && key < bkey)) { bv = v; bkey = key; }
    }
    redV[tid] = bv;
    redK[tid] = bkey;
    __syncthreads();
    for (int s = 128; s > 0; s >>= 1) {
      if (tid < s) {
        float ov = redV[tid + s];
        int ok = redK[tid + s];
        if (ov > redV[tid] || (ov == redV[tid] && ok < redK[tid])) {
          redV[tid] = ov;
          redK[tid] = ok;
        }
      }
      __syncthreads();
    }
    if (tid == 0) {
      float mv = redV[0];
      int mk = redK[0];
      int valid = (mv != 0.f) ? 1 : 0;
      int c = mk >> 14, l = mk & (HW - 1);
      winners[k * 3 + 0] = valid ? (float)c : -1.f;
      winners[k * 3 + 1] = valid ? (float)(l >> 7) : -1.f;
      winners[k * 3 + 2] = valid ? (float)(l & 127) : -1.f;
      bcValid[0] = valid ? 1.f : 0.f;
      bcKey[0] = mk;
    }
    __syncthreads();
    if (bcValid[0] > 0.f) {
      int mk = bcKey[0];
      int c = mk >> 14, h = (mk & (HW - 1)) >> 7, w = mk & 127;
      for (int i = tid; i < HW; i += 256) {
        int hh = i >> 7, ww = i & 127;
        int dh = hh - h; if (dh < 0) dh = -dh;
        int dw = ww - w; if (dw < 0) dw = -dw;
        bool m = (wchan[i] == c) || (dh <= 1 && dw <= 1);
        if (m) tot[i] = 0.f;
      }
    }
    __syncthreads();
  }
}

extern "C" void kernel_launch(void* const* d_in, const int* in_sizes, int n_in,
                              void* d_out, int out_size, void* d_ws, size_t ws_size,
                              hipStream_t stream) {
  const float* x = (const float*)d_in[0];
  const float* w1 = (const float*)d_in[1];
  const float* w2 = (const float*)d_in[2];
  (void)in_sizes; (void)n_in; (void)out_size; (void)ws_size;

  float* spk_out = (float*)d_out;
  float* pot_out = spk_out + 61440000;  // pot2 scratch == final pot at winner ch
  float* winners = spk_out + 122880000;

  uint8_t* ws = (uint8_t*)d_ws;
  unsigned long long* mp = (unsigned long long*)ws;  // 1,966,080 B u64 [15][HW]
  uint8_t* spk_pool = ws + 1966080;                  // 7,372,800 B u8
  int* win = (int*)(ws + 9338880);        //  65,536 B
  float* nspv = (float*)(ws + 9404416);   //  65,536 B
  float* valv = (float*)(ws + 9469952);   //  65,536 B
  float* sv = (float*)(ws + 9535488);     // 983,040 B  [15][16384]
  v2f* w1p = (v2f*)(ws + 10518528);       //  18,000 B
  v2f* w2p = (v2f*)(ws + 10536528);       // 270,000 B

  hipMemsetAsync(mp, 0, (size_t)15 * HW * 8, stream);
  hipLaunchKernelGGL(k_packw, dim3(141), dim3(256), 0, stream, w1, w2, w1p, w2p);
  hipLaunchKernelGGL(k_conv1, dim3(64, 5, 15), dim3(256), 0, stream, x, w1p, spk_pool);
  hipLaunchKernelGGL(k_conv2, dim3(16, 25, 15), dim3(256), 0, stream, spk_pool, w2p, pot_out, mp);
  hipLaunchKernelGGL(k_inhib, dim3(256), dim3(64), 0, stream, pot_out, mp, win, nspv, valv, sv);
  hipLaunchKernelGGL(k_final, dim3(250, 15), dim3(256), 0, stream, win, sv, spk_out, pot_out);
  hipLaunchKernelGGL(k_select, dim3(1), dim3(256), 0, stream, win, nspv, valv, winners);
}

// Round 9
// 1069.664 us; speedup vs baseline: 1.1665x; 1.0876x over previous
//
#include <hip/hip_runtime.h>
#include <cstdint>
#include <cstddef>

#define HW 16384  // 128*128
typedef float v2f __attribute__((ext_vector_type(2)));

// ---------------- weight pack: pairs of adjacent output channels ----------------
__global__ __launch_bounds__(256) void k_packw(const float* __restrict__ w1,
                                               const float* __restrict__ w2,
                                               v2f* __restrict__ w1p,
                                               v2f* __restrict__ w2p) {
  int i = blockIdx.x * 256 + threadIdx.x;
  if (i < 2250) {
    int m = i % 3, k = (i / 3) % 25, ic = (i / 75) % 6, ocg = i / 450;
    int g0 = ocg * 6 + 2 * m;
    w1p[i] = (v2f){w1[(g0 * 6 + ic) * 25 + k], w1[((g0 + 1) * 6 + ic) * 25 + k]};
  }
  i -= 2250;
  if (i >= 0 && i < 33750) {
    int m = i % 5, k = (i / 5) % 9, ic = (i / 45) % 30, ocg = i / 1350;
    int g0 = ocg * 10 + 2 * m;
    w2p[i] = (v2f){w2[(g0 * 30 + ic) * 9 + k], w2[((g0 + 1) * 30 + ic) * 9 + k]};
  }
}

// ---------------- conv1 + fire(15) + maxpool 2x2 (round-6 exact) ----------------
__global__ __launch_bounds__(256, 4) void k_conv1(const float* __restrict__ x,
                                                  const v2f* __restrict__ w1p,
                                                  uint8_t* __restrict__ spk_pool) {
  const int tile = blockIdx.x, ocg = blockIdx.y, t = blockIdx.z;
  const int oc0 = ocg * 6;
  const int tid = threadIdx.x;
  const int tx = tid & 15, ty = tid >> 4;
  const int px0 = (tile & 7) << 4, py0 = (tile >> 3) << 4;
  __shared__ float sx[2][36 * 38];
  const int iy0 = (py0 << 1) - 2, ix0 = (px0 << 1) - 2;  // pad=2

  int goff[6], soff[6];
  bool act[6];
#pragma unroll
  for (int j = 0; j < 6; ++j) {
    int idx = tid + 256 * j;
    bool a = idx < 1296;
    int r = idx / 36, c = idx - r * 36;
    int gy = iy0 + r, gx = ix0 + c;
    bool inb = a && (unsigned)gy < 256u && (unsigned)gx < 256u;
    goff[j] = inb ? ((gy << 8) + gx) : -1;
    soff[j] = a ? (r * 38 + c) : 0;
    act[j] = a;
  }

  v2f acc2[3][4];
#pragma unroll
  for (int m = 0; m < 3; ++m)
#pragma unroll
    for (int j = 0; j < 4; ++j) acc2[m][j] = (v2f){0.f, 0.f};

  const float* xt = x + ((size_t)(t * 6) << 16);
  float v[6];
#pragma unroll
  for (int j = 0; j < 6; ++j) v[j] = (goff[j] >= 0) ? xt[goff[j]] : 0.f;
#pragma unroll
  for (int j = 0; j < 6; ++j)
    if (act[j]) sx[0][soff[j]] = v[j];
  __syncthreads();

  for (int ic = 0; ic < 6; ++ic) {
    const int cur = ic & 1, nxt = cur ^ 1;
    if (ic < 5) {
      const float* xp = xt + ((size_t)(ic + 1) << 16);
#pragma unroll
      for (int j = 0; j < 6; ++j) v[j] = (goff[j] >= 0) ? xp[goff[j]] : 0.f;
    }
    float win_[6][6];
#pragma unroll
    for (int r = 0; r < 6; ++r) {
      float2 a = *(const float2*)&sx[cur][(2 * ty + r) * 38 + 2 * tx];
      float2 b = *(const float2*)&sx[cur][(2 * ty + r) * 38 + 2 * tx + 2];
      float2 c = *(const float2*)&sx[cur][(2 * ty + r) * 38 + 2 * tx + 4];
      win_[r][0] = a.x; win_[r][1] = a.y; win_[r][2] = b.x;
      win_[r][3] = b.y; win_[r][4] = c.x; win_[r][5] = c.y;
    }
    const v2f* wp = w1p + ((size_t)(ocg * 6 + ic) * 25) * 3;
#pragma unroll
    for (int k = 0; k < 25; ++k) {
      const int ky = k / 5, kx = k % 5;
      v2f s0 = (v2f){win_[ky][kx], win_[ky][kx]};
      v2f s1 = (v2f){win_[ky][kx + 1], win_[ky][kx + 1]};
      v2f s2 = (v2f){win_[ky + 1][kx], win_[ky + 1][kx]};
      v2f s3 = (v2f){win_[ky + 1][kx + 1], win_[ky + 1][kx + 1]};
#pragma unroll
      for (int m = 0; m < 3; ++m) {
        v2f wv = wp[k * 3 + m];  // block-uniform -> SGPR pair
        acc2[m][0] += wv * s0;
        acc2[m][1] += wv * s1;
        acc2[m][2] += wv * s2;
        acc2[m][3] += wv * s3;
      }
    }
    if (ic < 5) {
#pragma unroll
      for (int j = 0; j < 6; ++j)
        if (act[j]) sx[nxt][soff[j]] = v[j];
    }
    __syncthreads();
  }
#pragma unroll
  for (int g = 0; g < 6; ++g) {
    const int m = g >> 1;
    float a0 = (g & 1) ? acc2[m][0].y : acc2[m][0].x;
    float a1 = (g & 1) ? acc2[m][1].y : acc2[m][1].x;
    float a2 = (g & 1) ? acc2[m][2].y : acc2[m][2].x;
    float a3 = (g & 1) ? acc2[m][3].y : acc2[m][3].x;
    int spike = (a0 > 15.f) || (a1 > 15.f) || (a2 > 15.f) || (a3 > 15.f);
    spk_pool[((size_t)(t * 30 + oc0 + g) << 14) + ((size_t)(py0 + ty) << 7) + (px0 + tx)] =
        (uint8_t)spike;
  }
}

// ---------------- conv2 (pad=1) + fire(10) -> pot2, fused channel-max ----------
// __launch_bounds__(256,6): 1536 resident blocks >= 1500 grid -> single wave, no tail.
__global__ __launch_bounds__(256, 6) void k_conv2(const uint8_t* __restrict__ spk_pool,
                                                  const v2f* __restrict__ w2p,
                                                  float* __restrict__ pot2,
                                                  unsigned long long* __restrict__ mp) {
  const int tile = blockIdx.x, ocg = blockIdx.y, t = blockIdx.z;
  const int oc0 = ocg * 10;
  const int tid = threadIdx.x;
  const int bx = (tile & 3) << 5, by = (tile >> 2) << 5;
  const int tx = tid & 15, ty = tid >> 4;
  __shared__ float sS[2][34 * 40];
  __shared__ int sFlag[2][4];

  int goff[5], soff[5];
  bool act[5];
#pragma unroll
  for (int j = 0; j < 5; ++j) {
    int idx = tid + 256 * j;
    bool a = idx < 1156;
    int r = idx / 34, c = idx - r * 34;
    int gy = by - 1 + r, gx = bx - 1 + c;
    bool inb = a && (unsigned)gy < 128u && (unsigned)gx < 128u;
    goff[j] = inb ? ((gy << 7) + gx) : -1;
    soff[j] = a ? (r * 40 + c) : 0;
    act[j] = a;
  }

  v2f acc2[5][4];
#pragma unroll
  for (int m = 0; m < 5; ++m)
#pragma unroll
    for (int j = 0; j < 4; ++j) acc2[m][j] = (v2f){0.f, 0.f};

  const uint8_t* spk_t = spk_pool + ((size_t)(t * 30) << 14);
  float v[5];
#pragma unroll
  for (int j = 0; j < 5; ++j) v[j] = (goff[j] >= 0) ? (float)spk_t[goff[j]] : 0.f;
  {
    bool nz = (v[0] + v[1] + v[2] + v[3] + v[4]) != 0.f;
    bool wnz = __any(nz);
    if ((tid & 63) == 0) sFlag[0][tid >> 6] = wnz ? 1 : 0;
  }
#pragma unroll
  for (int j = 0; j < 5; ++j)
    if (act[j]) sS[0][soff[j]] = v[j];
  __syncthreads();

  for (int ic = 0; ic < 30; ++ic) {
    const int cur = ic & 1, nxt = cur ^ 1;
    if (ic < 29) {
      const uint8_t* spc = spk_t + ((size_t)(ic + 1) << 14);
#pragma unroll
      for (int j = 0; j < 5; ++j) v[j] = (goff[j] >= 0) ? (float)spc[goff[j]] : 0.f;
    }
    const int flag = sFlag[cur][0] | sFlag[cur][1] | sFlag[cur][2] | sFlag[cur][3];
    if (flag) {
      float win_[4][4];
#pragma unroll
      for (int r = 0; r < 4; ++r) {
        float2 a = *(const float2*)&sS[cur][(2 * ty + r) * 40 + 2 * tx];
        float2 b = *(const float2*)&sS[cur][(2 * ty + r) * 40 + 2 * tx + 2];
        win_[r][0] = a.x; win_[r][1] = a.y; win_[r][2] = b.x; win_[r][3] = b.y;
      }
      const v2f* wp = w2p + ((size_t)(ocg * 30 + ic) * 9) * 5;
#pragma unroll
      for (int k = 0; k < 9; ++k) {
        const int kr = k / 3, ks = k % 3;
        v2f s0 = (v2f){win_[kr][ks], win_[kr][ks]};
        v2f s1 = (v2f){win_[kr][ks + 1], win_[kr][ks + 1]};
        v2f s2 = (v2f){win_[kr + 1][ks], win_[kr + 1][ks]};
        v2f s3 = (v2f){win_[kr + 1][ks + 1], win_[kr + 1][ks + 1]};
#pragma unroll
        for (int m = 0; m < 5; ++m) {
          v2f wv = wp[k * 5 + m];  // block-uniform -> SGPR pair
          acc2[m][0] += wv * s0;
          acc2[m][1] += wv * s1;
          acc2[m][2] += wv * s2;
          acc2[m][3] += wv * s3;
        }
      }
    }
    if (ic < 29) {
      bool nz = (v[0] + v[1] + v[2] + v[3] + v[4]) != 0.f;
      bool wnz = __any(nz);
      if ((tid & 63) == 0) sFlag[nxt][tid >> 6] = wnz ? 1 : 0;
#pragma unroll
      for (int j = 0; j < 5; ++j)
        if (act[j]) sS[nxt][soff[j]] = v[j];
    }
    __syncthreads();
  }

  // fire + write pot2 + per-loc max/argmax over this block's 10 oc
  const int gy = by + 2 * ty, gx = bx + 2 * tx;
  float mxv[4] = {0.f, 0.f, 0.f, 0.f};
  int mxc[4] = {0, 0, 0, 0};
#pragma unroll
  for (int g = 0; g < 10; ++g) {
    const int m = g >> 1;
    float a0 = (g & 1) ? acc2[m][0].y : acc2[m][0].x;
    float a1 = (g & 1) ? acc2[m][1].y : acc2[m][1].x;
    float a2 = (g & 1) ? acc2[m][2].y : acc2[m][2].x;
    float a3 = (g & 1) ? acc2[m][3].y : acc2[m][3].x;
    float* outp = pot2 + ((size_t)(t * 250 + oc0 + g) << 14);
    float2 v0, v1;
    v0.x = a0 > 10.f ? a0 : 0.f;
    v0.y = a1 > 10.f ? a1 : 0.f;
    v1.x = a2 > 10.f ? a2 : 0.f;
    v1.y = a3 > 10.f ? a3 : 0.f;
    *(float2*)&outp[((size_t)gy << 7) + gx] = v0;
    *(float2*)&outp[((size_t)(gy + 1) << 7) + gx] = v1;
    if (v0.x > mxv[0]) { mxv[0] = v0.x; mxc[0] = g; }
    if (v0.y > mxv[1]) { mxv[1] = v0.y; mxc[1] = g; }
    if (v1.x > mxv[2]) { mxv[2] = v1.x; mxc[2] = g; }
    if (v1.y > mxv[3]) { mxv[3] = v1.y; mxc[3] = g; }
  }
  unsigned long long* mpt = mp + (size_t)t * HW;
  const int locs[4] = {(gy << 7) + gx, (gy << 7) + gx + 1,
                       ((gy + 1) << 7) + gx, ((gy + 1) << 7) + gx + 1};
#pragma unroll
  for (int j = 0; j < 4; ++j) {
    unsigned long long pk =
        ((unsigned long long)__float_as_uint(mxv[j]) << 32) |
        (unsigned long long)(1023 - (oc0 + mxc[j]));
    atomicMax(&mpt[locs[j]], pk);
  }
}

// ---------------- inhibition combine per location ----------------
__global__ __launch_bounds__(64) void k_inhib(const float* __restrict__ pot2,
                                              const unsigned long long* __restrict__ mp,
                                              int* __restrict__ win,
                                              float* __restrict__ nspv,
                                              float* __restrict__ valv,
                                              float* __restrict__ sv) {
  const int loc = (blockIdx.x << 6) + threadIdx.x;
  int cnt = 0;
  float last = 0.f;
  unsigned long long pks[15];
#pragma unroll
  for (int t = 0; t < 15; ++t) {
    pks[t] = mp[t * HW + loc];
    float v = __uint_as_float((unsigned)(pks[t] >> 32));
    cnt += (v > 0.f) ? 1 : 0;
    if (t == 14) last = v;
  }
  const int spiked = (last > 0.f) ? 1 : 0;
  int ft = 15 - cnt;
  if (ft > 14) ft = 14;
  if (ft < 0) ft = 0;
  int wc = 1023 - (int)(pks[ft] & 1023ULL);
  if ((unsigned)wc > 249u) wc = 0;
  int nsp = 0;
#pragma unroll
  for (int t = 0; t < 15; ++t) {
    float v = pot2[((size_t)(t * 250 + wc) << 14) + loc];
    v = spiked ? v : 0.f;
    sv[t * HW + loc] = v;
    nsp += (v > 0.f) ? 1 : 0;
  }
  int ft2 = 15 - nsp;
  if (ft2 > 14) ft2 = 14;
  float value = spiked ? pot2[((size_t)(ft2 * 250 + wc) << 14) + loc] : 0.f;
  win[loc] = spiked ? wc : -1;
  nspv[loc] = (float)nsp;
  valv[loc] = value;
}

// ---------------- finalize: loc-major (round-6 exact) ----------------
// grid (64, 15), block 256. Thread = 1 loc, loops 250 channels.
__global__ __launch_bounds__(256) void k_final(const int* __restrict__ win,
                                               const float* __restrict__ sv,
                                               float* __restrict__ spk_out,
                                               float* __restrict__ pot_out) {
  const int t = blockIdx.y;
  const int loc = (blockIdx.x << 8) + threadIdx.x;
  const int wcL = win[loc];
  const float v = sv[t * HW + loc];
  const float s = (v > 0.f) ? 1.f : 0.f;
  float* pp = pot_out + ((size_t)(t * 250) << 14) + loc;
  float* sp = spk_out + ((size_t)(t * 250) << 14) + loc;
  for (int c = 0; c < 250; ++c) {
    pp[(size_t)c << 14] = (c == wcL) ? v : 0.f;
    sp[(size_t)c << 14] = (c == wcL) ? s : 0.f;
  }
}

// ---------------- k-winner selection (single block) ----------------
__global__ __launch_bounds__(256) void k_select(const int* __restrict__ win,
                                                const float* __restrict__ nspv,
                                                const float* __restrict__ valv,
                                                float* __restrict__ winners) {
  __shared__ float tot[HW];
  __shared__ int wchan[HW];
  __shared__ float redV[256];
  __shared__ int redK[256];
  __shared__ float bcValid[1];
  __shared__ int bcKey[1];
  const int tid = threadIdx.x;

  float lmax = 0.f;
  for (int i = tid; i < HW; i += 256) {
    wchan[i] = win[i];
    lmax = fmaxf(lmax, valv[i]);
  }
  redV[tid] = lmax;
  __syncthreads();
  for (int s = 128; s > 0; s >>= 1) {
    if (tid < s) redV[tid] = fmaxf(redV[tid], redV[tid + s]);
    __syncthreads();
  }
  const float v15 = redV[0] * 15.f;
  __syncthreads();
  for (int i = tid; i < HW; i += 256) tot[i] = nspv[i] * (valv[i] + v15);
  __syncthreads();

  for (int k = 0; k < 8; ++k) {
    float bv = -1.f;
    int bkey = 0x7fffffff;
    for (int i = tid; i < HW; i += 256) {
      float v = tot[i];
      int key = (wchan[i] << 14) + i;
      if (v > bv || (v == bv && key < bkey)) { bv = v; bkey = key; }
    }
    redV[tid] = bv;
    redK[tid] = bkey;
    __syncthreads();
    for (int s = 128; s > 0; s >>= 1) {
      if (tid < s) {
        float ov = redV[tid + s];
        int ok = redK[tid + s];
        if (ov > redV[tid] || (ov == redV[tid] && ok < redK[tid])) {
          redV[tid] = ov;
          redK[tid] = ok;
        }
      }
      __syncthreads();
    }
    if (tid == 0) {
      float mv = redV[0];
      int mk = redK[0];
      int valid = (mv != 0.f) ? 1 : 0;
      int c = mk >> 14, l = mk & (HW - 1);
      winners[k * 3 + 0] = valid ? (float)c : -1.f;
      winners[k * 3 + 1] = valid ? (float)(l >> 7) : -1.f;
      winners[k * 3 + 2] = valid ? (float)(l & 127) : -1.f;
      bcValid[0] = valid ? 1.f : 0.f;
      bcKey[0] = mk;
    }
    __syncthreads();
    if (bcValid[0] > 0.f) {
      int mk = bcKey[0];
      int c = mk >> 14, h = (mk & (HW - 1)) >> 7, w = mk & 127;
      for (int i = tid; i < HW; i += 256) {
        int hh = i >> 7, ww = i & 127;
        int dh = hh - h; if (dh < 0) dh = -dh;
        int dw = ww - w; if (dw < 0) dw = -dw;
        bool m = (wchan[i] == c) || (dh <= 1 && dw <= 1);
        if (m) tot[i] = 0.f;
      }
    }
    __syncthreads();
  }
}

extern "C" void kernel_launch(void* const* d_in, const int* in_sizes, int n_in,
                              void* d_out, int out_size, void* d_ws, size_t ws_size,
                              hipStream_t stream) {
  const float* x = (const float*)d_in[0];
  const float* w1 = (const float*)d_in[1];
  const float* w2 = (const float*)d_in[2];
  (void)in_sizes; (void)n_in; (void)out_size; (void)ws_size;

  float* spk_out = (float*)d_out;
  float* pot_out = spk_out + 61440000;  // pot2 scratch == final pot at winner ch
  float* winners = spk_out + 122880000;

  uint8_t* ws = (uint8_t*)d_ws;
  unsigned long long* mp = (unsigned long long*)ws;  // 1,966,080 B u64 [15][HW]
  uint8_t* spk_pool = ws + 1966080;                  // 7,372,800 B u8
  int* win = (int*)(ws + 9338880);        //  65,536 B
  float* nspv = (float*)(ws + 9404416);   //  65,536 B
  float* valv = (float*)(ws + 9469952);   //  65,536 B
  float* sv = (float*)(ws + 9535488);     // 983,040 B  [15][16384]
  v2f* w1p = (v2f*)(ws + 10518528);       //  18,000 B
  v2f* w2p = (v2f*)(ws + 10536528);       // 270,000 B

  hipMemsetAsync(mp, 0, (size_t)15 * HW * 8, stream);
  hipLaunchKernelGGL(k_packw, dim3(141), dim3(256), 0, stream, w1, w2, w1p, w2p);
  hipLaunchKernelGGL(k_conv1, dim3(64, 5, 15), dim3(256), 0, stream, x, w1p, spk_pool);
  hipLaunchKernelGGL(k_conv2, dim3(16, 25, 15), dim3(256), 0, stream, spk_pool, w2p, pot_out, mp);
  hipLaunchKernelGGL(k_inhib, dim3(256), dim3(64), 0, stream, pot_out, mp, win, nspv, valv, sv);
  hipLaunchKernelGGL(k_final, dim3(64, 15), dim3(256), 0, stream, win, sv, spk_out, pot_out);
  hipLaunchKernelGGL(k_select, dim3(1), dim3(256), 0, stream, win, nspv, valv, winners);
}